// Round 1
// baseline (279.502 us; speedup 1.0000x reference)
//
#include <hip/hip_runtime.h>
#include <math.h>

// Problem constants
constexpr int NPTS = 30000;
constexpr int CIN  = 128;
constexpr int OC   = 128;   // O
constexpr int NH   = 8;     // heads
constexpr int NS   = 16;    // neighbors
constexpr int DH   = 16;    // O/H
constexpr int OSH  = 16;    // O/SHARE
constexpr float EPSF = 1e-5f;

// ---------------------------------------------------------------------------
// Kernel 1: fused QKV projection.  y = x @ W + b for W in {Wq,Wk,Wv}.
// 64 rows per block, x tile staged in LDS (stride 132 keeps float4 alignment),
// 8 rows x 4 cols register tile per thread.
// ---------------------------------------------------------------------------
__global__ __launch_bounds__(256) void qkv_kernel(
    const float* __restrict__ x,
    const float* __restrict__ Wq, const float* __restrict__ bq,
    const float* __restrict__ Wk, const float* __restrict__ bk,
    const float* __restrict__ Wv, const float* __restrict__ bv,
    float* __restrict__ yq, float* __restrict__ yk, float* __restrict__ yv)
{
    const float* W; const float* b; float* y;
    switch (blockIdx.y) {
        case 0:  W = Wq; b = bq; y = yq; break;
        case 1:  W = Wk; b = bk; y = yk; break;
        default: W = Wv; b = bv; y = yv; break;
    }
    const int row0 = blockIdx.x * 64;
    const int t  = threadIdx.x;
    const int og = t & 31;   // output group: cols og*4 .. og*4+3
    const int rg = t >> 5;   // row group: rows rg*8 .. rg*8+7

    __shared__ float xs[64][132];   // padded row stride (multiple of 4 floats)

    // Stage 64 rows of x (guarded for the 30000 % 64 tail)
    #pragma unroll
    for (int i = 0; i < 8; ++i) {
        int idx4 = t + 256 * i;          // 2048 float4s total
        int row  = idx4 >> 5;            // 32 float4 per row
        int c4   = idx4 & 31;
        int grow = row0 + row;
        float4 val = make_float4(0.f, 0.f, 0.f, 0.f);
        if (grow < NPTS) val = *(const float4*)(x + grow * CIN + c4 * 4);
        *(float4*)&xs[row][c4 * 4] = val;
    }
    __syncthreads();

    float acc[8][4];
    #pragma unroll
    for (int r = 0; r < 8; ++r)
        #pragma unroll
        for (int c = 0; c < 4; ++c) acc[r][c] = 0.f;

    const float* Wo = W + og * 4;
    for (int k4 = 0; k4 < 32; ++k4) {
        float4 w0 = *(const float4*)(Wo + (k4 * 4 + 0) * OC);
        float4 w1 = *(const float4*)(Wo + (k4 * 4 + 1) * OC);
        float4 w2 = *(const float4*)(Wo + (k4 * 4 + 2) * OC);
        float4 w3 = *(const float4*)(Wo + (k4 * 4 + 3) * OC);
        #pragma unroll
        for (int r = 0; r < 8; ++r) {
            float4 xv4 = *(const float4*)&xs[rg * 8 + r][k4 * 4];
            acc[r][0] += xv4.x * w0.x + xv4.y * w1.x + xv4.z * w2.x + xv4.w * w3.x;
            acc[r][1] += xv4.x * w0.y + xv4.y * w1.y + xv4.z * w2.y + xv4.w * w3.y;
            acc[r][2] += xv4.x * w0.z + xv4.y * w1.z + xv4.z * w2.z + xv4.w * w3.z;
            acc[r][3] += xv4.x * w0.w + xv4.y * w1.w + xv4.z * w2.w + xv4.w * w3.w;
        }
    }

    float4 bias = *(const float4*)(b + og * 4);
    #pragma unroll
    for (int r = 0; r < 8; ++r) {
        int n = row0 + rg * 8 + r;
        if (n < NPTS) {
            float4 o4 = make_float4(acc[r][0] + bias.x, acc[r][1] + bias.y,
                                    acc[r][2] + bias.z, acc[r][3] + bias.w);
            *(float4*)(y + n * OC + og * 4) = o4;
        }
    }
}

// ---------------------------------------------------------------------------
// Kernel 2: per-point attention. One block per point, 128 threads = (s,h).
// Thread (s,h) owns the 16-wide head slice for pe, r, and output contribution.
// ---------------------------------------------------------------------------
__global__ __launch_bounds__(128) void attn_kernel(
    const float* __restrict__ p, const int* __restrict__ idx,
    const float* __restrict__ xq, const float* __restrict__ xk, const float* __restrict__ xv,
    const float* __restrict__ Wp1, const float* __restrict__ bp1,
    const float* __restrict__ gp,  const float* __restrict__ betap,
    const float* __restrict__ Wp2, const float* __restrict__ bp2,
    const float* __restrict__ gw1, const float* __restrict__ betaw1,
    const float* __restrict__ Ww1, const float* __restrict__ bw1,
    const float* __restrict__ gw2, const float* __restrict__ betaw2,
    const float* __restrict__ Ww2, const float* __restrict__ bw2,
    float* __restrict__ out)
{
    const int n = blockIdx.x;
    const int t = threadIdx.x;   // 0..127
    const int s = t >> 3;        // neighbor
    const int h = t & 7;         // head

    __shared__ float s_t[NS][4];        // relu(LN(pr@Wp1)) per neighbor
    __shared__ float s_logit[NS][NH];
    __shared__ float s_contrib[NS][OC]; // 8 KB

    // --- per-neighbor tiny MLP input (threads 0..15, one per s) ---
    if (t < NS) {
        int ss = t;
        int j = idx[n * NS + ss];
        float pr0 = p[j * 3 + 0] - p[n * 3 + 0];
        float pr1 = p[j * 3 + 1] - p[n * 3 + 1];
        float pr2 = p[j * 3 + 2] - p[n * 3 + 2];
        float u[3];
        #pragma unroll
        for (int c = 0; c < 3; ++c)
            u[c] = bp1[c] + pr0 * Wp1[0 * 3 + c] + pr1 * Wp1[1 * 3 + c] + pr2 * Wp1[2 * 3 + c];
        float m   = (u[0] + u[1] + u[2]) * (1.f / 3.f);
        float d0 = u[0] - m, d1 = u[1] - m, d2 = u[2] - m;
        float var = (d0 * d0 + d1 * d1 + d2 * d2) * (1.f / 3.f);
        float inv = rsqrtf(var + EPSF);
        #pragma unroll
        for (int c = 0; c < 3; ++c) {
            float yv = (u[c] - m) * inv * gp[c] + betap[c];
            s_t[ss][c] = fmaxf(yv, 0.f);
        }
    }
    __syncthreads();

    const int j = idx[n * NS + s];
    const float t0 = s_t[s][0], t1 = s_t[s][1], t2 = s_t[s][2];
    const int obase = h * DH;

    // pe for this head slice (registers only)
    float pe[DH];
    #pragma unroll
    for (int d = 0; d < DH; ++d) {
        int o = obase + d;
        pe[d] = bp2[o] + t0 * Wp2[0 * OC + o] + t1 * Wp2[1 * OC + o] + t2 * Wp2[2 * OC + o];
    }

    // gather k,v and build r = kg + pe - xq
    float vv[DH], r[DH];
    {
        const float4* k4 = (const float4*)(xk + (long)j * OC + obase);
        const float4* v4 = (const float4*)(xv + (long)j * OC + obase);
        const float4* q4 = (const float4*)(xq + (long)n * OC + obase);
        #pragma unroll
        for (int q = 0; q < 4; ++q) {
            float4 kk = k4[q], vvv = v4[q], qq = q4[q];
            r[q * 4 + 0] = kk.x + pe[q * 4 + 0] - qq.x;
            r[q * 4 + 1] = kk.y + pe[q * 4 + 1] - qq.y;
            r[q * 4 + 2] = kk.z + pe[q * 4 + 2] - qq.z;
            r[q * 4 + 3] = kk.w + pe[q * 4 + 3] - qq.w;
            vv[q * 4 + 0] = vvv.x; vv[q * 4 + 1] = vvv.y;
            vv[q * 4 + 2] = vvv.z; vv[q * 4 + 3] = vvv.w;
        }
    }

    // LN over D=16 + relu
    float a[DH];
    {
        float m = 0.f;
        #pragma unroll
        for (int d = 0; d < DH; ++d) m += r[d];
        m *= (1.f / DH);
        float var = 0.f;
        #pragma unroll
        for (int d = 0; d < DH; ++d) { float dd = r[d] - m; var += dd * dd; }
        var *= (1.f / DH);
        float inv = rsqrtf(var + EPSF);
        #pragma unroll
        for (int d = 0; d < DH; ++d)
            a[d] = fmaxf((r[d] - m) * inv * gw1[d] + betaw1[d], 0.f);
    }

    // w1 = a @ Ww1 + bw1
    float w1[OSH];
    #pragma unroll
    for (int o2 = 0; o2 < OSH; ++o2) w1[o2] = bw1[o2];
    #pragma unroll
    for (int d = 0; d < DH; ++d) {
        float av = a[d];
        #pragma unroll
        for (int o2 = 0; o2 < OSH; ++o2) w1[o2] += av * Ww1[d * OSH + o2];
    }

    // LN over OS=16 + relu
    float bvec[OSH];
    {
        float m = 0.f;
        #pragma unroll
        for (int o2 = 0; o2 < OSH; ++o2) m += w1[o2];
        m *= (1.f / OSH);
        float var = 0.f;
        #pragma unroll
        for (int o2 = 0; o2 < OSH; ++o2) { float dd = w1[o2] - m; var += dd * dd; }
        var *= (1.f / OSH);
        float inv = rsqrtf(var + EPSF);
        #pragma unroll
        for (int o2 = 0; o2 < OSH; ++o2)
            bvec[o2] = fmaxf((w1[o2] - m) * inv * gw2[o2] + betaw2[o2], 0.f);
    }

    // logit = mean(bvec @ Ww2 + bw2)
    float logit = 0.f;
    #pragma unroll
    for (int o2 = 0; o2 < OSH; ++o2) {
        float acc = bw2[o2];
        #pragma unroll
        for (int d = 0; d < OSH; ++d) acc += bvec[d] * Ww2[d * OSH + o2];
        logit += acc;
    }
    logit *= (1.f / OSH);

    s_logit[s][h] = logit;
    __syncthreads();

    // softmax over s for this head (redundant across the 16 threads sharing h)
    float mx = -1e30f;
    #pragma unroll
    for (int ss = 0; ss < NS; ++ss) mx = fmaxf(mx, s_logit[ss][h]);
    float denom = 0.f;
    #pragma unroll
    for (int ss = 0; ss < NS; ++ss) denom += __expf(s_logit[ss][h] - mx);
    float w = __expf(logit - mx) / denom;

    // contribution (vg + pe) * w
    #pragma unroll
    for (int d = 0; d < DH; ++d)
        s_contrib[s][obase + d] = (vv[d] + pe[d]) * w;
    __syncthreads();

    // reduce over s: thread t sums column t
    float acc = 0.f;
    #pragma unroll
    for (int ss = 0; ss < NS; ++ss) acc += s_contrib[ss][t];
    out[(long)n * OC + t] = acc;
}

// ---------------------------------------------------------------------------
extern "C" void kernel_launch(void* const* d_in, const int* in_sizes, int n_in,
                              void* d_out, int out_size, void* d_ws, size_t ws_size,
                              hipStream_t stream) {
    const float* p     = (const float*)d_in[0];
    const float* x     = (const float*)d_in[1];
    const int*   idx   = (const int*)d_in[2];
    const float* Wq    = (const float*)d_in[3];
    const float* bq    = (const float*)d_in[4];
    const float* Wk    = (const float*)d_in[5];
    const float* bk    = (const float*)d_in[6];
    const float* Wv    = (const float*)d_in[7];
    const float* bv    = (const float*)d_in[8];
    const float* Wp1   = (const float*)d_in[9];
    const float* bp1   = (const float*)d_in[10];
    const float* gp    = (const float*)d_in[11];
    const float* betap = (const float*)d_in[12];
    const float* Wp2   = (const float*)d_in[13];
    const float* bp2   = (const float*)d_in[14];
    const float* gw1   = (const float*)d_in[15];
    const float* betaw1= (const float*)d_in[16];
    const float* Ww1   = (const float*)d_in[17];
    const float* bw1   = (const float*)d_in[18];
    const float* gw2   = (const float*)d_in[19];
    const float* betaw2= (const float*)d_in[20];
    const float* Ww2   = (const float*)d_in[21];
    const float* bw2   = (const float*)d_in[22];
    float* out = (float*)d_out;

    float* xq = (float*)d_ws;                 // N*128 floats
    float* xk = xq + (size_t)NPTS * OC;
    float* xv = xk + (size_t)NPTS * OC;

    dim3 g1((NPTS + 63) / 64, 3);
    qkv_kernel<<<g1, 256, 0, stream>>>(x, Wq, bq, Wk, bk, Wv, bv, xq, xk, xv);

    attn_kernel<<<NPTS, 128, 0, stream>>>(p, idx, xq, xk, xv,
                                          Wp1, bp1, gp, betap, Wp2, bp2,
                                          gw1, betaw1, Ww1, bw1,
                                          gw2, betaw2, Ww2, bw2, out);
}

// Round 2
// 239.476 us; speedup vs baseline: 1.1671x; 1.1671x over previous
//
#include <hip/hip_runtime.h>
#include <math.h>

typedef unsigned int  uint;
typedef unsigned short ushort;

// Problem constants
constexpr int NPTS = 30000;
constexpr int CIN  = 128;
constexpr int OC   = 128;   // O
constexpr int NH   = 8;     // heads
constexpr int NS   = 16;    // neighbors
constexpr int DH   = 16;    // O/H
constexpr int OSH  = 16;    // O/SHARE
constexpr float EPSF = 1e-5f;

__device__ __forceinline__ ushort f2bf(float f) {
    uint u = __float_as_uint(f);
    u += 0x7fff + ((u >> 16) & 1);   // RNE
    return (ushort)(u >> 16);
}
__device__ __forceinline__ void bf2f2(uint u, float& f0, float& f1) {
    f0 = __uint_as_float(u << 16);
    f1 = __uint_as_float(u & 0xffff0000u);
}

// ---------------------------------------------------------------------------
// Kernel 1: fused QKV projection, W staged in LDS.
// Block: 64 rows x 128 cols of one matrix. blockIdx.y selects {q,k,v}.
// q output fp32; k,v outputs bf16 (halves the gather traffic in attn).
// ---------------------------------------------------------------------------
__global__ __launch_bounds__(256) void qkv_kernel(
    const float* __restrict__ x,
    const float* __restrict__ Wq, const float* __restrict__ bq,
    const float* __restrict__ Wk, const float* __restrict__ bk,
    const float* __restrict__ Wv, const float* __restrict__ bv,
    float* __restrict__ yq, ushort* __restrict__ yk, ushort* __restrict__ yv)
{
    const int mat = blockIdx.y;
    const float* W = (mat == 0) ? Wq : (mat == 1 ? Wk : Wv);
    const float* b = (mat == 0) ? bq : (mat == 1 ? bk : bv);

    const int row0 = blockIdx.x * 64;
    const int t  = threadIdx.x;
    const int og = t & 31;   // cols og*4 .. og*4+3
    const int rg = t >> 5;   // rows rg*8 .. rg*8+7

    __shared__ float xs[64][36];    // 64 rows x 32 k (pad 36: b128-aligned rows)
    __shared__ float wt[32][132];   // 32 k x 128 cols (pad 132)

    float acc[8][4];
    #pragma unroll
    for (int r = 0; r < 8; ++r)
        #pragma unroll
        for (int c = 0; c < 4; ++c) acc[r][c] = 0.f;

    for (int kt = 0; kt < 4; ++kt) {
        const int k0 = kt * 32;
        // stage x tile: 64 rows x 32 cols = 512 float4, 2 per thread
        #pragma unroll
        for (int i = 0; i < 2; ++i) {
            int id  = t + 256 * i;
            int row = id >> 3;
            int c4  = id & 7;
            int grow = row0 + row;
            float4 v = make_float4(0.f, 0.f, 0.f, 0.f);
            if (grow < NPTS) v = *(const float4*)(x + (size_t)grow * CIN + k0 + c4 * 4);
            *(float4*)&xs[row][c4 * 4] = v;
        }
        // stage W tile: 32 k x 128 cols = 1024 float4, 4 per thread
        #pragma unroll
        for (int i = 0; i < 4; ++i) {
            int id = t + 256 * i;
            int kr = id >> 5;
            int c4 = id & 31;
            float4 wv = *(const float4*)(W + (size_t)(k0 + kr) * OC + c4 * 4);
            *(float4*)&wt[kr][c4 * 4] = wv;
        }
        __syncthreads();

        #pragma unroll
        for (int kq = 0; kq < 8; ++kq) {
            const int kb = kq * 4;
            float4 a[8];
            #pragma unroll
            for (int r = 0; r < 8; ++r) a[r] = *(const float4*)&xs[rg * 8 + r][kb];
            float4 b0 = *(const float4*)&wt[kb + 0][og * 4];
            float4 b1 = *(const float4*)&wt[kb + 1][og * 4];
            float4 b2 = *(const float4*)&wt[kb + 2][og * 4];
            float4 b3 = *(const float4*)&wt[kb + 3][og * 4];
            #pragma unroll
            for (int r = 0; r < 8; ++r) {
                acc[r][0] = fmaf(a[r].x, b0.x, fmaf(a[r].y, b1.x, fmaf(a[r].z, b2.x, fmaf(a[r].w, b3.x, acc[r][0]))));
                acc[r][1] = fmaf(a[r].x, b0.y, fmaf(a[r].y, b1.y, fmaf(a[r].z, b2.y, fmaf(a[r].w, b3.y, acc[r][1]))));
                acc[r][2] = fmaf(a[r].x, b0.z, fmaf(a[r].y, b1.z, fmaf(a[r].z, b2.z, fmaf(a[r].w, b3.z, acc[r][2]))));
                acc[r][3] = fmaf(a[r].x, b0.w, fmaf(a[r].y, b1.w, fmaf(a[r].z, b2.w, fmaf(a[r].w, b3.w, acc[r][3]))));
            }
        }
        __syncthreads();
    }

    float4 bias = *(const float4*)(b + og * 4);
    ushort* ybf = (mat == 1) ? yk : yv;
    #pragma unroll
    for (int r = 0; r < 8; ++r) {
        int n = row0 + rg * 8 + r;
        if (n < NPTS) {
            float o0 = acc[r][0] + bias.x, o1 = acc[r][1] + bias.y;
            float o2 = acc[r][2] + bias.z, o3 = acc[r][3] + bias.w;
            if (mat == 0) {
                *(float4*)(yq + (size_t)n * OC + og * 4) = make_float4(o0, o1, o2, o3);
            } else {
                uint lo = (uint)f2bf(o0) | ((uint)f2bf(o1) << 16);
                uint hi = (uint)f2bf(o2) | ((uint)f2bf(o3) << 16);
                *(uint2*)(ybf + (size_t)n * OC + og * 4) = make_uint2(lo, hi);
            }
        }
    }
}

// ---------------------------------------------------------------------------
// Kernel 2: per-point attention. One block per point, 128 threads = (s,h).
// k/v gathered as bf16. Second matvec fused into a dot with rowmean(Ww2).
// ---------------------------------------------------------------------------
__global__ __launch_bounds__(128) void attn_kernel(
    const float* __restrict__ p, const int* __restrict__ idx,
    const float* __restrict__ xq, const ushort* __restrict__ xk, const ushort* __restrict__ xv,
    const float* __restrict__ Wp1, const float* __restrict__ bp1,
    const float* __restrict__ gp,  const float* __restrict__ betap,
    const float* __restrict__ Wp2, const float* __restrict__ bp2,
    const float* __restrict__ gw1, const float* __restrict__ betaw1,
    const float* __restrict__ Ww1, const float* __restrict__ bw1,
    const float* __restrict__ gw2, const float* __restrict__ betaw2,
    const float* __restrict__ Ww2, const float* __restrict__ bw2,
    float* __restrict__ out)
{
    const int n = blockIdx.x;
    const int t = threadIdx.x;   // 0..127
    const int s = t >> 3;        // neighbor
    const int h = t & 7;         // head

    __shared__ float s_t[NS][4];        // relu(LN(pr@Wp1)) per neighbor
    __shared__ float s_rm[OSH + 1];     // rowmean(Ww2)[d], [16] = mean(bw2)
    __shared__ float s_logit[NS][NH];
    __shared__ float s_mx[NH];
    __shared__ float s_inv[NH];
    __shared__ float s_contrib[NS][OC]; // 8 KB

    // --- per-neighbor tiny MLP (threads 0..15), rowmean(Ww2) (32..47) ---
    if (t < NS) {
        int ss = t;
        int j = idx[n * NS + ss];
        float pr0 = p[j * 3 + 0] - p[n * 3 + 0];
        float pr1 = p[j * 3 + 1] - p[n * 3 + 1];
        float pr2 = p[j * 3 + 2] - p[n * 3 + 2];
        float u[3];
        #pragma unroll
        for (int c = 0; c < 3; ++c)
            u[c] = bp1[c] + pr0 * Wp1[0 * 3 + c] + pr1 * Wp1[1 * 3 + c] + pr2 * Wp1[2 * 3 + c];
        float m   = (u[0] + u[1] + u[2]) * (1.f / 3.f);
        float d0 = u[0] - m, d1 = u[1] - m, d2 = u[2] - m;
        float var = (d0 * d0 + d1 * d1 + d2 * d2) * (1.f / 3.f);
        float inv = rsqrtf(var + EPSF);
        #pragma unroll
        for (int c = 0; c < 3; ++c)
            s_t[ss][c] = fmaxf((u[c] - m) * inv * gp[c] + betap[c], 0.f);
    } else if (t < 48) {
        int d = t - 32;
        float acc = 0.f;
        #pragma unroll
        for (int o2 = 0; o2 < OSH; ++o2) acc += Ww2[d * OSH + o2];
        s_rm[d] = acc * (1.f / OSH);
    } else if (t == 48) {
        float acc = 0.f;
        #pragma unroll
        for (int o2 = 0; o2 < OSH; ++o2) acc += bw2[o2];
        s_rm[OSH] = acc * (1.f / OSH);
    }
    __syncthreads();

    const int j = idx[n * NS + s];
    const float t0 = s_t[s][0], t1 = s_t[s][1], t2 = s_t[s][2];
    const int obase = h * DH;

    // pe for this head slice (registers only)
    float pe[DH];
    #pragma unroll
    for (int d = 0; d < DH; ++d) {
        int o = obase + d;
        pe[d] = bp2[o] + t0 * Wp2[0 * OC + o] + t1 * Wp2[1 * OC + o] + t2 * Wp2[2 * OC + o];
    }

    // gather k,v (bf16) and build r = kg + pe - xq
    float vv[DH], r[DH];
    {
        const uint4* k4 = (const uint4*)(xk + (size_t)j * OC + obase);
        const uint4* v4 = (const uint4*)(xv + (size_t)j * OC + obase);
        const float4* q4 = (const float4*)(xq + (size_t)n * OC + obase);
        uint4 ku0 = k4[0], ku1 = k4[1];
        uint4 vu0 = v4[0], vu1 = v4[1];
        float kf[DH];
        bf2f2(ku0.x, kf[0], kf[1]);   bf2f2(ku0.y, kf[2], kf[3]);
        bf2f2(ku0.z, kf[4], kf[5]);   bf2f2(ku0.w, kf[6], kf[7]);
        bf2f2(ku1.x, kf[8], kf[9]);   bf2f2(ku1.y, kf[10], kf[11]);
        bf2f2(ku1.z, kf[12], kf[13]); bf2f2(ku1.w, kf[14], kf[15]);
        bf2f2(vu0.x, vv[0], vv[1]);   bf2f2(vu0.y, vv[2], vv[3]);
        bf2f2(vu0.z, vv[4], vv[5]);   bf2f2(vu0.w, vv[6], vv[7]);
        bf2f2(vu1.x, vv[8], vv[9]);   bf2f2(vu1.y, vv[10], vv[11]);
        bf2f2(vu1.z, vv[12], vv[13]); bf2f2(vu1.w, vv[14], vv[15]);
        #pragma unroll
        for (int q = 0; q < 4; ++q) {
            float4 qq = q4[q];
            r[q * 4 + 0] = kf[q * 4 + 0] + pe[q * 4 + 0] - qq.x;
            r[q * 4 + 1] = kf[q * 4 + 1] + pe[q * 4 + 1] - qq.y;
            r[q * 4 + 2] = kf[q * 4 + 2] + pe[q * 4 + 2] - qq.z;
            r[q * 4 + 3] = kf[q * 4 + 3] + pe[q * 4 + 3] - qq.w;
        }
    }

    // LN over D=16 + relu
    float a[DH];
    {
        float m = 0.f;
        #pragma unroll
        for (int d = 0; d < DH; ++d) m += r[d];
        m *= (1.f / DH);
        float var = 0.f;
        #pragma unroll
        for (int d = 0; d < DH; ++d) { float dd = r[d] - m; var += dd * dd; }
        var *= (1.f / DH);
        float inv = rsqrtf(var + EPSF);
        #pragma unroll
        for (int d = 0; d < DH; ++d)
            a[d] = fmaxf((r[d] - m) * inv * gw1[d] + betaw1[d], 0.f);
    }

    // w1 = a @ Ww1 + bw1
    float w1[OSH];
    #pragma unroll
    for (int o2 = 0; o2 < OSH; ++o2) w1[o2] = bw1[o2];
    #pragma unroll
    for (int d = 0; d < DH; ++d) {
        float av = a[d];
        #pragma unroll
        for (int o2 = 0; o2 < OSH; ++o2) w1[o2] = fmaf(av, Ww1[d * OSH + o2], w1[o2]);
    }

    // LN over OS=16 + relu, then fused (@Ww2 + bw2).mean(-1)
    float logit;
    {
        float m = 0.f;
        #pragma unroll
        for (int o2 = 0; o2 < OSH; ++o2) m += w1[o2];
        m *= (1.f / OSH);
        float var = 0.f;
        #pragma unroll
        for (int o2 = 0; o2 < OSH; ++o2) { float dd = w1[o2] - m; var += dd * dd; }
        var *= (1.f / OSH);
        float inv = rsqrtf(var + EPSF);
        logit = s_rm[OSH];
        #pragma unroll
        for (int o2 = 0; o2 < OSH; ++o2) {
            float bv2 = fmaxf((w1[o2] - m) * inv * gw2[o2] + betaw2[o2], 0.f);
            logit = fmaf(bv2, s_rm[o2], logit);
        }
    }

    s_logit[s][h] = logit;
    __syncthreads();

    // softmax stats once per head
    if (t < NH) {
        float mx = -1e30f;
        #pragma unroll
        for (int ss = 0; ss < NS; ++ss) mx = fmaxf(mx, s_logit[ss][t]);
        float denom = 0.f;
        #pragma unroll
        for (int ss = 0; ss < NS; ++ss) denom += __expf(s_logit[ss][t] - mx);
        s_mx[t] = mx;
        s_inv[t] = 1.f / denom;
    }
    __syncthreads();

    float w = __expf(logit - s_mx[h]) * s_inv[h];

    // contribution (vg + pe) * w
    #pragma unroll
    for (int d = 0; d < DH; ++d)
        s_contrib[s][obase + d] = (vv[d] + pe[d]) * w;
    __syncthreads();

    // reduce over s: thread t sums column t (conflict-free: bank = t%32)
    float acc = 0.f;
    #pragma unroll
    for (int ss = 0; ss < NS; ++ss) acc += s_contrib[ss][t];
    out[(size_t)n * OC + t] = acc;
}

// ---------------------------------------------------------------------------
extern "C" void kernel_launch(void* const* d_in, const int* in_sizes, int n_in,
                              void* d_out, int out_size, void* d_ws, size_t ws_size,
                              hipStream_t stream) {
    const float* p     = (const float*)d_in[0];
    const float* x     = (const float*)d_in[1];
    const int*   idx   = (const int*)d_in[2];
    const float* Wq    = (const float*)d_in[3];
    const float* bq    = (const float*)d_in[4];
    const float* Wk    = (const float*)d_in[5];
    const float* bk    = (const float*)d_in[6];
    const float* Wv    = (const float*)d_in[7];
    const float* bv    = (const float*)d_in[8];
    const float* Wp1   = (const float*)d_in[9];
    const float* bp1   = (const float*)d_in[10];
    const float* gp    = (const float*)d_in[11];
    const float* betap = (const float*)d_in[12];
    const float* Wp2   = (const float*)d_in[13];
    const float* bp2   = (const float*)d_in[14];
    const float* gw1   = (const float*)d_in[15];
    const float* betaw1= (const float*)d_in[16];
    const float* Ww1   = (const float*)d_in[17];
    const float* bw1   = (const float*)d_in[18];
    const float* gw2   = (const float*)d_in[19];
    const float* betaw2= (const float*)d_in[20];
    const float* Ww2   = (const float*)d_in[21];
    const float* bw2   = (const float*)d_in[22];
    float* out = (float*)d_out;

    float*  xq = (float*)d_ws;                       // N*128 fp32
    ushort* xk = (ushort*)(xq + (size_t)NPTS * OC);  // N*128 bf16
    ushort* xv = xk + (size_t)NPTS * OC;             // N*128 bf16

    dim3 g1((NPTS + 63) / 64, 3);
    qkv_kernel<<<g1, 256, 0, stream>>>(x, Wq, bq, Wk, bk, Wv, bv, xq, xk, xv);

    attn_kernel<<<NPTS, 128, 0, stream>>>(p, idx, xq, xk, xv,
                                          Wp1, bp1, gp, betap, Wp2, bp2,
                                          gw1, betaw1, Ww1, bw1,
                                          gw2, betaw2, Ww2, bw2, out);
}